// Round 9
// baseline (66.496 us; speedup 1.0000x reference)
//
#include <hip/hip_runtime.h>

#define NN 10000    // nodes
#define NE 25000    // edges
#define DF 128      // features
#define SB 256      // block size
#define NBLK ((NE + SB - 1) / SB)          // 98 scan blocks
#define NEWXB ((NE * 32 + SB - 1) / SB)    // 3125 newx blocks

typedef float f4 __attribute__((ext_vector_type(4)));   // native vec for NT stores

// ---------------------------------------------------------------------------
// K1: tiny init — head[]=-1, lookback flags=0, link-barrier counter=0.
// ---------------------------------------------------------------------------
__global__ void k_init(int* __restrict__ head, int* __restrict__ gFlag,
                       int* __restrict__ gBar) {
    int tid = blockIdx.x * blockDim.x + threadIdx.x;
    if (tid < NN) head[tid] = -1;
    if (tid < NBLK) gFlag[tid] = 0;
    if (tid == 0) *gBar = 0;
}

// ---------------------------------------------------------------------------
// K2: ONE dispatch, two roles.
//  blocks [0, NBLK): link slice -> grid-barrier(98) -> cnt_edge ->
//                    decoupled-lookback exclusive scan -> rowStart[0..NE]
//  blocks [NBLK, ..): new_x[e] = ((x[u]+x[v])*0.5 + ea[e])*0.5
// Barrier/lookback are deadlock-free: newx blocks never wait (they retire),
// so the 98 scan blocks are eventually co-resident; publish-then-spin.
// Cross-XCD: head via device-scope atomicExch; nxt via agent-scope atomic
// store/load; __threadfence before barrier arrival.
// ---------------------------------------------------------------------------
__global__ __launch_bounds__(SB) void k_mega(const float* __restrict__ x,
                                             const float* __restrict__ ea,
                                             const int* __restrict__ c0,
                                             const int* __restrict__ c1,
                                             int* __restrict__ head,
                                             int* __restrict__ nxt,
                                             int* __restrict__ gFlag,
                                             int* __restrict__ gBar,
                                             int* __restrict__ rowStart,
                                             float* __restrict__ out) {
    int b = blockIdx.x, t = threadIdx.x;

    if (b >= NBLK) {
        // ---- newx role ----
        int tid = (b - NBLK) * SB + t;
        if (tid >= NE * 32) return;
        int e = tid >> 5, q = tid & 31;
        int u = c0[e], v = c1[e];
        float4 a  = ((const float4*)(x + (size_t)u * DF))[q];
        float4 bb = ((const float4*)(x + (size_t)v * DF))[q];
        float4 c  = ((const float4*)(ea + (size_t)e * DF))[q];
        float4 r;
        r.x = ((a.x + bb.x) * 0.5f + c.x) * 0.5f;
        r.y = ((a.y + bb.y) * 0.5f + c.y) * 0.5f;
        r.z = ((a.z + bb.z) * 0.5f + c.z) * 0.5f;
        r.w = ((a.w + bb.w) * 0.5f + c.w) * 0.5f;
        ((float4*)(out + (size_t)e * DF))[q] = r;
        return;
    }

    // ---- scan role ----
    int i = b * SB + t;

    // link phase (slice of NE)
    if (i < NE) {
        int prev = atomicExch(&head[c0[i]], i);
        __hip_atomic_store(&nxt[i], prev, __ATOMIC_RELAXED, __HIP_MEMORY_SCOPE_AGENT);
    }
    __threadfence();
    __syncthreads();
    if (t == 0) {
        atomicAdd(gBar, 1);
        while (atomicAdd(gBar, 0) < NBLK) __builtin_amdgcn_s_sleep(1);
    }
    __syncthreads();
    __threadfence();

    // cnt phase
    int cnt = 0;
    if (i < NE) {
        int u = c0[i], v = c1[i];
        int j = __hip_atomic_load(&head[v], __ATOMIC_RELAXED, __HIP_MEMORY_SCOPE_AGENT);
        while (j != -1) {
            if (c1[j] != u) ++cnt;
            j = __hip_atomic_load(&nxt[j], __ATOMIC_RELAXED, __HIP_MEMORY_SCOPE_AGENT);
        }
    }

    // LDS inclusive scan
    __shared__ int sc[SB];
    __shared__ int sr[SB];
    sc[t] = cnt;
    __syncthreads();
    for (int off = 1; off < SB; off <<= 1) {
        int add = (t >= off) ? sc[t - off] : 0;
        __syncthreads();
        sc[t] += add;
        __syncthreads();
    }
    int blockSum = sc[SB - 1];
    if (t == 0) atomicExch(&gFlag[b], blockSum + 1);   // publish
    int val = 0;
    if (t < b) {                                       // parallel lookback
        int v2;
        do { v2 = atomicAdd(&gFlag[t], 0); } while (v2 == 0);
        val = v2 - 1;
    }
    sr[t] = val;
    __syncthreads();
    for (int off = SB / 2; off > 0; off >>= 1) {
        if (t < off) sr[t] += sr[t + off];
        __syncthreads();
    }
    int base = sr[0];
    if (i < NE) rowStart[i] = base + sc[t] - cnt;      // exclusive
    if (b == NBLK - 1 && t == 0) rowStart[NE] = base + blockSum;
}

// ---------------------------------------------------------------------------
// K3: one wave per edge i (wave-uniform i).
//  - single list walk: lane l owns element l; rank-by-value via shfl loop.
//  - attr: wave writes TWO identical rows per store (f4/lane, 1KB/inst).
//  - nontemporal stores: outputs are write-once, keep L2 for newx gathers.
// ---------------------------------------------------------------------------
__global__ void k_emit(const float* __restrict__ newx,
                       const int* __restrict__ c0, const int* __restrict__ c1,
                       const int* __restrict__ head, const int* __restrict__ nxt,
                       const int* __restrict__ rowStart,
                       float* __restrict__ outRows, float* __restrict__ outCols,
                       float* __restrict__ outAttr) {
    int gtid = blockIdx.x * blockDim.x + threadIdx.x;
    int i = gtid >> 6, lane = gtid & 63;
    if (i >= NE) return;
    int base = rowStart[i];
    int cnt  = rowStart[i + 1] - base;
    if (cnt == 0) return;
    int u = c0[i], v = c1[i];

    // walk list once; lane l records element l
    int myj = -1, B = 0;
    for (int j = head[v]; j != -1; j = nxt[j], ++B)
        if (B == lane) myj = j;

    if (B <= 64) {
        int myc1 = (myj >= 0) ? c1[myj] : -1;
        bool keep = (myj >= 0) && (myc1 != u);
        int rank = 0;
        for (int q = 0; q < B; ++q) {
            int jq = __shfl(myj, q);
            int cq = __shfl(myc1, q);
            if (cq != u && jq < myj) ++rank;
        }
        if (keep) {
            __builtin_nontemporal_store((float)i, &outRows[base + rank]);
            __builtin_nontemporal_store((float)myj, &outCols[base + rank]);
        }
    } else {
        int pos = 0;
        for (int j = head[v]; j != -1; j = nxt[j], ++pos) {
            if ((pos & 63) != lane) continue;
            if (c1[j] == u) continue;
            int rank = 0;
            for (int j2 = head[v]; j2 != -1; j2 = nxt[j2])
                rank += (c1[j2] != u && j2 < j) ? 1 : 0;
            __builtin_nontemporal_store((float)i, &outRows[base + rank]);
            __builtin_nontemporal_store((float)j, &outCols[base + rank]);
        }
    }

    // attr: cnt identical copies of new_x[v]; 2 rows per store instruction
    f4 val = ((const f4*)(newx + (size_t)v * DF))[lane & 31];
    for (int tt = (lane >> 5); tt < cnt; tt += 2)
        __builtin_nontemporal_store(val,
            &((f4*)(outAttr + (size_t)(base + tt) * DF))[lane & 31]);
}

// ---------------------------------------------------------------------------

extern "C" void kernel_launch(void* const* d_in, const int* in_sizes, int n_in,
                              void* d_out, int out_size, void* d_ws, size_t ws_size,
                              hipStream_t stream) {
    const float* x  = (const float*)d_in[0];
    const float* ea = (const float*)d_in[1];
    const int*   ei = (const int*)d_in[2];
    const int* c0 = ei;        // edge_index[0]
    const int* c1 = ei + NE;   // edge_index[1]

    float* out = (float*)d_out;
    int E_lg = (out_size - NE * DF) / (DF + 2);
    if (E_lg < 0) E_lg = 0;

    float* out_newx = out;                      // NE*DF
    float* out_rows = out + (size_t)NE * DF;    // E_lg
    float* out_cols = out_rows + E_lg;          // E_lg
    float* out_attr = out_cols + E_lg;          // E_lg*DF

    int* ws       = (int*)d_ws;
    int* head     = ws;                         // NN
    int* nxt      = head + NN;                  // NE
    int* rowStart = nxt + NE;                   // NE+1
    int* gFlag    = rowStart + NE + 1;          // NBLK
    int* gBar     = gFlag + NBLK;               // 1

    k_init<<<(NN + SB - 1) / SB, SB, 0, stream>>>(head, gFlag, gBar);
    k_mega<<<NBLK + NEWXB, SB, 0, stream>>>(x, ea, c0, c1, head, nxt,
                                            gFlag, gBar, rowStart, out_newx);
    k_emit<<<(NE * 64 + SB - 1) / SB, SB, 0, stream>>>(out_newx, c0, c1, head, nxt,
                                                       rowStart, out_rows, out_cols, out_attr);
}

// Round 10
// 44.510 us; speedup vs baseline: 1.4939x; 1.4939x over previous
//
#include <hip/hip_runtime.h>

#define NN 10000    // nodes
#define NE 25000    // edges
#define DF 128      // features
#define SB 256      // small block size
#define CHUNK 64    // edges per scan/emit block
#define NCH ((NE + CHUNK - 1) / CHUNK)     // 391 blocks

typedef float f4 __attribute__((ext_vector_type(4)));   // native vec for NT stores

// ---------------------------------------------------------------------------
// K1: new_x[e] = ((x[u]+x[v])*0.5 + ea[e])*0.5 (32 thr/edge, float4)
//     + init head[]=-1 and lookback flags=0 (reuses the big grid).
// ---------------------------------------------------------------------------
__global__ void k_newx_init(const float* __restrict__ x, const float* __restrict__ ea,
                            const int* __restrict__ c0, const int* __restrict__ c1,
                            float* __restrict__ out, int* __restrict__ head,
                            int* __restrict__ gFlag) {
    int tid = blockIdx.x * blockDim.x + threadIdx.x;
    if (tid < NN) head[tid] = -1;
    if (tid < NCH) gFlag[tid] = 0;
    if (tid >= NE * 32) return;
    int e = tid >> 5, q = tid & 31;
    int u = c0[e], v = c1[e];
    float4 a  = ((const float4*)(x + (size_t)u * DF))[q];
    float4 bb = ((const float4*)(x + (size_t)v * DF))[q];
    float4 c  = ((const float4*)(ea + (size_t)e * DF))[q];
    float4 r;
    r.x = ((a.x + bb.x) * 0.5f + c.x) * 0.5f;
    r.y = ((a.y + bb.y) * 0.5f + c.y) * 0.5f;
    r.z = ((a.z + bb.z) * 0.5f + c.z) * 0.5f;
    r.w = ((a.w + bb.w) * 0.5f + c.w) * 0.5f;
    ((float4*)(out + (size_t)e * DF))[q] = r;
}

// ---------------------------------------------------------------------------
// K2: per-node linked lists in one pass. Separate dispatch ON PURPOSE:
// the kernel boundary is the coherence point that lets K3 walk the lists
// with normal cached loads (R9 lesson: intra-kernel cross-block handoff
// forces slow agent-scope loads on the dependent walk).
// ---------------------------------------------------------------------------
__global__ void k_link(const int* __restrict__ c0,
                       int* __restrict__ head, int* __restrict__ nxt) {
    int j = blockIdx.x * blockDim.x + threadIdx.x;
    if (j >= NE) return;
    nxt[j] = atomicExch(&head[c0[j]], j);
}

// ---------------------------------------------------------------------------
// K3: fused cnt + decoupled-lookback scan + emit. Block b owns edges
// [b*64, b*64+64). Wave 0: per-lane list-walk count, shfl inclusive scan,
// publish aggregate (status 1), windowed 64-lane lookback to resolve base,
// publish inclusive (status 2). All 391 blocks (16 waves, tiny LDS) are
// co-resident (cap 512) -> spin-safe under any dispatch order. Then 16
// waves emit 4 edges each: shfl rank-by-value for rows/cols order, attr =
// cnt identical copies of new_x[c1[i]] (2 rows / 1KB per store, NT).
// ---------------------------------------------------------------------------
__global__ __launch_bounds__(1024) void k_scan_emit(
        const float* __restrict__ newx,
        const int* __restrict__ c0, const int* __restrict__ c1,
        const int* __restrict__ head, const int* __restrict__ nxt,
        int* __restrict__ gFlag,
        float* __restrict__ outRows, float* __restrict__ outCols,
        float* __restrict__ outAttr) {
    __shared__ int sCnt[CHUNK];
    __shared__ int sExc[CHUNK];
    __shared__ int sBase;
    int b = blockIdx.x, t = threadIdx.x;
    int wave = t >> 6, lane = t & 63;
    int e0 = b * CHUNK;

    if (wave == 0) {
        // ---- count phase: lane l owns edge e0+l ----
        int e = e0 + lane;
        int cnt = 0;
        if (e < NE) {
            int u = c0[e], v = c1[e];
            for (int j = head[v]; j != -1; j = nxt[j])
                if (c1[j] != u) ++cnt;
        }
        // ---- inclusive shfl scan over 64 lanes ----
        int incl = cnt;
        for (int off = 1; off < 64; off <<= 1) {
            int vv = __shfl_up(incl, off, 64);
            if (lane >= off) incl += vv;
        }
        int agg = __shfl(incl, 63);
        sCnt[lane] = cnt;
        sExc[lane] = incl - cnt;
        // ---- publish aggregate, lookback, publish inclusive ----
        int base = 0;
        if (b == 0) {
            if (lane == 0) atomicExch(&gFlag[0], (2 << 30) | agg);
        } else {
            if (lane == 0) atomicExch(&gFlag[b], (1 << 30) | agg);
            int p = b - 1;
            while (true) {
                int idx = p - lane;
                int st, sm;
                if (idx < 0) { st = 2; sm = 0; }
                else {
                    int f;
                    do {
                        f = __hip_atomic_load(&gFlag[idx], __ATOMIC_ACQUIRE,
                                              __HIP_MEMORY_SCOPE_AGENT);
                        st = (unsigned)f >> 30;
                    } while (st == 0);
                    sm = f & 0x3FFFFFFF;
                }
                unsigned long long inclMask = __ballot(st == 2);
                int contrib;
                if (inclMask) {
                    int l0 = __ffsll(inclMask) - 1;   // nearest inclusive
                    contrib = (lane <= l0) ? sm : 0;
                } else {
                    contrib = sm;
                }
                for (int off = 32; off; off >>= 1)
                    contrib += __shfl_down(contrib, off, 64);
                contrib = __shfl(contrib, 0);
                base += contrib;
                if (inclMask) break;
                p -= 64;
            }
            if (lane == 0) atomicExch(&gFlag[b], (2 << 30) | (base + agg));
        }
        if (lane == 0) sBase = base;
    }
    __syncthreads();

    // ---- emit phase: wave w handles edges e0 + w*4 .. +4 ----
    int gBase = sBase;
    for (int k = 0; k < 4; ++k) {
        int el = wave * 4 + k;              // 16 waves * 4 = 64
        int i = e0 + el;
        if (i >= NE) break;
        int cnt = sCnt[el];
        if (cnt == 0) continue;
        int base = gBase + sExc[el];
        int u = c0[i], v = c1[i];

        // walk list once; lane l records element l
        int myj = -1, B = 0;
        for (int j = head[v]; j != -1; j = nxt[j], ++B)
            if (B == lane) myj = j;

        if (B <= 64) {
            int myc1 = (myj >= 0) ? c1[myj] : -1;
            bool keep = (myj >= 0) && (myc1 != u);
            int rank = 0;
            for (int q = 0; q < B; ++q) {
                int jq = __shfl(myj, q);
                int cq = __shfl(myc1, q);
                if (cq != u && jq < myj) ++rank;
            }
            if (keep) {
                __builtin_nontemporal_store((float)i, &outRows[base + rank]);
                __builtin_nontemporal_store((float)myj, &outCols[base + rank]);
            }
        } else {
            int pos = 0;
            for (int j = head[v]; j != -1; j = nxt[j], ++pos) {
                if ((pos & 63) != lane) continue;
                if (c1[j] == u) continue;
                int rank = 0;
                for (int j2 = head[v]; j2 != -1; j2 = nxt[j2])
                    rank += (c1[j2] != u && j2 < j) ? 1 : 0;
                __builtin_nontemporal_store((float)i, &outRows[base + rank]);
                __builtin_nontemporal_store((float)j, &outCols[base + rank]);
            }
        }

        // attr: cnt identical copies of new_x[v]; 2 rows / 1KB per store
        f4 val = ((const f4*)(newx + (size_t)v * DF))[lane & 31];
        for (int tt = (lane >> 5); tt < cnt; tt += 2)
            __builtin_nontemporal_store(val,
                &((f4*)(outAttr + (size_t)(base + tt) * DF))[lane & 31]);
    }
}

// ---------------------------------------------------------------------------

extern "C" void kernel_launch(void* const* d_in, const int* in_sizes, int n_in,
                              void* d_out, int out_size, void* d_ws, size_t ws_size,
                              hipStream_t stream) {
    const float* x  = (const float*)d_in[0];
    const float* ea = (const float*)d_in[1];
    const int*   ei = (const int*)d_in[2];
    const int* c0 = ei;        // edge_index[0]
    const int* c1 = ei + NE;   // edge_index[1]

    float* out = (float*)d_out;
    int E_lg = (out_size - NE * DF) / (DF + 2);
    if (E_lg < 0) E_lg = 0;

    float* out_newx = out;                      // NE*DF
    float* out_rows = out + (size_t)NE * DF;    // E_lg
    float* out_cols = out_rows + E_lg;          // E_lg
    float* out_attr = out_cols + E_lg;          // E_lg*DF

    int* ws    = (int*)d_ws;
    int* head  = ws;                            // NN
    int* nxt   = head + NN;                     // NE
    int* gFlag = nxt + NE;                      // NCH

    k_newx_init<<<(NE * 32 + SB - 1) / SB, SB, 0, stream>>>(x, ea, c0, c1, out_newx,
                                                            head, gFlag);
    k_link<<<(NE + SB - 1) / SB, SB, 0, stream>>>(c0, head, nxt);
    k_scan_emit<<<NCH, 1024, 0, stream>>>(out_newx, c0, c1, head, nxt, gFlag,
                                          out_rows, out_cols, out_attr);
}